// Round 1
// baseline (327.770 us; speedup 1.0000x reference)
//
#include <hip/hip_runtime.h>
#include <hip/hip_bf16.h>

#define BB 4096
#define TT 200
#define LL 8
#define VV 64
#define CC 16
#define NBERN 32
#define CLIP 20.0f

// One wave (64 lanes) per batch element. lane = output var v.
// 4 waves per 256-thread block -> grid = B/4 = 1024 blocks.
__global__ __launch_bounds__(256) void vargllvm_fused(
    const float* __restrict__ eps,        // (B,T,L)
    const float* __restrict__ u,          // (B,1,V)
    const float* __restrict__ x,          // (B,T,C)
    const float* __restrict__ A,          // (L,L)
    const float* __restrict__ logvar_z1,  // (L)
    const float* __restrict__ beta0,      // (L)
    const float* __restrict__ beta1,      // (L)
    const float* __restrict__ intercepts, // (V)
    const float* __restrict__ wz,         // (L,V)
    const float* __restrict__ wx,         // (C,V)
    const float* __restrict__ logvar_u,   // (V)
    float* __restrict__ linpar_out,       // (B,T,V)
    float* __restrict__ condmean_out)     // (B,T,V)
{
    const int wave = threadIdx.x >> 6;
    const int lane = threadIdx.x & 63;
    const int b    = blockIdx.x * 4 + wave;
    const int v    = lane;

    // ---- per-lane (per-v) weights ----
    float wxv[CC];
#pragma unroll
    for (int c = 0; c < CC; ++c) wxv[c] = wx[c * VV + v];
    float wzv[LL];
#pragma unroll
    for (int l = 0; l < LL; ++l) wzv[l] = wz[l * VV + v];
    const float base = intercepts[v] + u[(size_t)b * VV + v] * __expf(0.5f * logvar_u[v]);

    // ---- wave-uniform params (compiler: scalar loads -> SGPRs) ----
    float Ar[LL][LL];
#pragma unroll
    for (int l = 0; l < LL; ++l)
#pragma unroll
        for (int j = 0; j < LL; ++j) Ar[l][j] = A[l * LL + j];
    float b0[LL], b1[LL];
#pragma unroll
    for (int j = 0; j < LL; ++j) { b0[j] = beta0[j]; b1[j] = beta1[j]; }

    const float* epsb = eps + (size_t)b * TT * LL;
    const float* xb   = x   + (size_t)b * TT * CC;
    float* lp = linpar_out   + (size_t)b * TT * VV + v;
    float* cm = condmean_out + (size_t)b * TT * VV + v;

    // ---- z0 ----
    float z[LL];
#pragma unroll
    for (int j = 0; j < LL; ++j)
        z[j] = epsb[j] * __expf(0.5f * logvar_z1[j]);

    for (int t = 0; t < TT; ++t) {
        if (t > 0) {
            // z_t = z_{t-1} @ A + beta0 + beta1*t + eps_t   (all lanes, redundant)
            float zn[LL];
            const float tf = (float)t;
#pragma unroll
            for (int j = 0; j < LL; ++j) {
                float a = fmaf(b1[j], tf, b0[j]) + epsb[t * LL + j];
#pragma unroll
                for (int l = 0; l < LL; ++l) a = fmaf(z[l], Ar[l][j], a);
                zn[j] = a;
            }
#pragma unroll
            for (int j = 0; j < LL; ++j) z[j] = zn[j];
        }

        // linpar[b,t,v]
        float acc = base;
#pragma unroll
        for (int c = 0; c < CC; ++c) acc = fmaf(xb[t * CC + c], wxv[c], acc);
#pragma unroll
        for (int l = 0; l < LL; ++l) acc = fmaf(z[l], wzv[l], acc);
        acc = fminf(fmaxf(acc, -CLIP), CLIP);

        float cmv;
        if (v < NBERN) {
            cmv = 1.0f / (1.0f + __expf(-acc));   // sigmoid
        } else {
            cmv = __expf(acc);                    // poisson link
        }

        lp[(size_t)t * VV] = acc;   // coalesced: 64 lanes x 4B contiguous
        cm[(size_t)t * VV] = cmv;
    }
}

extern "C" void kernel_launch(void* const* d_in, const int* in_sizes, int n_in,
                              void* d_out, int out_size, void* d_ws, size_t ws_size,
                              hipStream_t stream) {
    const float* eps        = (const float*)d_in[0];
    const float* u          = (const float*)d_in[1];
    const float* x          = (const float*)d_in[2];
    const float* A          = (const float*)d_in[3];
    const float* logvar_z1  = (const float*)d_in[4];
    const float* beta0      = (const float*)d_in[5];
    const float* beta1      = (const float*)d_in[6];
    const float* intercepts = (const float*)d_in[7];
    const float* wz         = (const float*)d_in[8];
    const float* wx         = (const float*)d_in[9];
    const float* logvar_u   = (const float*)d_in[10];

    float* linpar   = (float*)d_out;
    float* condmean = (float*)d_out + (size_t)BB * TT * VV;

    dim3 grid(BB / 4);
    dim3 block(256);
    hipLaunchKernelGGL(vargllvm_fused, grid, block, 0, stream,
                       eps, u, x, A, logvar_z1, beta0, beta1,
                       intercepts, wz, wx, logvar_u, linpar, condmean);
}

// Round 2
// 169.889 us; speedup vs baseline: 1.9293x; 1.9293x over previous
//
#include <hip/hip_runtime.h>
#include <hip/hip_bf16.h>

#define BB 4096
#define TT 200
#define LL 8
#define VV 64
#define CC 16
#define NBERN 32
#define CLIP 20.0f
#define TC 20                      // t-chunk per wave in link kernel
#define NCH (TT / TC)              // 10 chunks per b

// ---------------- Phase A: z recurrence, one thread per b ----------------
__global__ __launch_bounds__(64) void var1_kernel(
    const float* __restrict__ eps,        // (B,T,L)
    const float* __restrict__ A,          // (L,L)
    const float* __restrict__ logvar_z1,  // (L)
    const float* __restrict__ beta0,      // (L)
    const float* __restrict__ beta1,      // (L)
    float* __restrict__ zout)             // (B,T,L) in ws
{
    const int b = blockIdx.x * 64 + threadIdx.x;

    // wave-uniform params -> SGPRs
    float Ar[LL][LL];
#pragma unroll
    for (int l = 0; l < LL; ++l)
#pragma unroll
        for (int j = 0; j < LL; ++j) Ar[l][j] = A[l * LL + j];
    float b0[LL], b1[LL], s1[LL];
#pragma unroll
    for (int j = 0; j < LL; ++j) {
        b0[j] = beta0[j];
        b1[j] = beta1[j];
        s1[j] = __expf(0.5f * logvar_z1[j]);
    }

    const float* ep = eps + (size_t)b * TT * LL;
    float* zb = zout + (size_t)b * TT * LL;

    // t = 0
    float4 e0 = *(const float4*)(ep);
    float4 e1 = *(const float4*)(ep + 4);
    float z[LL];
    z[0] = e0.x * s1[0]; z[1] = e0.y * s1[1]; z[2] = e0.z * s1[2]; z[3] = e0.w * s1[3];
    z[4] = e1.x * s1[4]; z[5] = e1.y * s1[5]; z[6] = e1.z * s1[6]; z[7] = e1.w * s1[7];
    *(float4*)(zb)     = make_float4(z[0], z[1], z[2], z[3]);
    *(float4*)(zb + 4) = make_float4(z[4], z[5], z[6], z[7]);

    // prefetch t=1
    float4 n0 = *(const float4*)(ep + LL);
    float4 n1 = *(const float4*)(ep + LL + 4);

    for (int t = 1; t < TT; ++t) {
        float cur[LL];
        cur[0] = n0.x; cur[1] = n0.y; cur[2] = n0.z; cur[3] = n0.w;
        cur[4] = n1.x; cur[5] = n1.y; cur[6] = n1.z; cur[7] = n1.w;
        if (t + 1 < TT) {                       // prefetch next eps row
            n0 = *(const float4*)(ep + (size_t)(t + 1) * LL);
            n1 = *(const float4*)(ep + (size_t)(t + 1) * LL + 4);
        }
        const float tf = (float)t;
        float zn[LL];
#pragma unroll
        for (int j = 0; j < LL; ++j) {
            float a = fmaf(b1[j], tf, b0[j]) + cur[j];
#pragma unroll
            for (int l = 0; l < LL; ++l) a = fmaf(z[l], Ar[l][j], a);
            zn[j] = a;
        }
#pragma unroll
        for (int j = 0; j < LL; ++j) z[j] = zn[j];
        *(float4*)(zb + (size_t)t * LL)     = make_float4(z[0], z[1], z[2], z[3]);
        *(float4*)(zb + (size_t)t * LL + 4) = make_float4(z[4], z[5], z[6], z[7]);
    }
}

// ---------------- Phase B: link map, one wave per (b, t-chunk) ----------------
__global__ __launch_bounds__(256) void link_kernel(
    const float* __restrict__ z,          // (B,T,L) from ws
    const float* __restrict__ u,          // (B,1,V)
    const float* __restrict__ x,          // (B,T,C)
    const float* __restrict__ intercepts, // (V)
    const float* __restrict__ wz,         // (L,V)
    const float* __restrict__ wx,         // (C,V)
    const float* __restrict__ logvar_u,   // (V)
    float* __restrict__ linpar_out,       // (B,T,V)
    float* __restrict__ condmean_out)     // (B,T,V)
{
    const int w    = threadIdx.x >> 6;
    const int lane = threadIdx.x & 63;
    const int gw   = blockIdx.x * 4 + w;       // global wave id
    const int b    = gw / NCH;
    const int t0   = (gw - b * NCH) * TC;
    const int v    = lane;

    __shared__ __align__(16) float xs[4][TC * CC];  // 4 x 320 floats
    __shared__ __align__(16) float zs[4][TC * LL];  // 4 x 160 floats

    // per-lane weights
    float wxv[CC];
#pragma unroll
    for (int c = 0; c < CC; ++c) wxv[c] = wx[c * VV + v];
    float wzv[LL];
#pragma unroll
    for (int l = 0; l < LL; ++l) wzv[l] = wz[l * VV + v];
    const float base = intercepts[v] + u[(size_t)b * VV + v] * __expf(0.5f * logvar_u[v]);

    // stage chunk (wave-private: no barrier needed, same wave writes & reads)
    const float* gx = x + ((size_t)b * TT + t0) * CC;
    const float* gz = z + ((size_t)b * TT + t0) * LL;
#pragma unroll
    for (int i = lane; i < TC * CC; i += 64) xs[w][i] = gx[i];
#pragma unroll
    for (int i = lane; i < TC * LL; i += 64) zs[w][i] = gz[i];

    float* lp = linpar_out   + ((size_t)b * TT + t0) * VV + v;
    float* cm = condmean_out + ((size_t)b * TT + t0) * VV + v;

    for (int tt = 0; tt < TC; ++tt) {
        const float4* xr = (const float4*)&xs[w][tt * CC];
        const float4* zr = (const float4*)&zs[w][tt * LL];
        float acc = base;
#pragma unroll
        for (int q = 0; q < 4; ++q) {
            float4 xv = xr[q];
            acc = fmaf(xv.x, wxv[q * 4 + 0], acc);
            acc = fmaf(xv.y, wxv[q * 4 + 1], acc);
            acc = fmaf(xv.z, wxv[q * 4 + 2], acc);
            acc = fmaf(xv.w, wxv[q * 4 + 3], acc);
        }
#pragma unroll
        for (int q = 0; q < 2; ++q) {
            float4 zv = zr[q];
            acc = fmaf(zv.x, wzv[q * 4 + 0], acc);
            acc = fmaf(zv.y, wzv[q * 4 + 1], acc);
            acc = fmaf(zv.z, wzv[q * 4 + 2], acc);
            acc = fmaf(zv.w, wzv[q * 4 + 3], acc);
        }
        acc = fminf(fmaxf(acc, -CLIP), CLIP);
        float cmv = (v < NBERN) ? (1.0f / (1.0f + __expf(-acc))) : __expf(acc);
        lp[(size_t)tt * VV] = acc;
        cm[(size_t)tt * VV] = cmv;
    }
}

// ---------------- fallback: R0 fused kernel (if ws too small) ----------------
__global__ __launch_bounds__(256) void vargllvm_fused(
    const float* __restrict__ eps, const float* __restrict__ u,
    const float* __restrict__ x, const float* __restrict__ A,
    const float* __restrict__ logvar_z1, const float* __restrict__ beta0,
    const float* __restrict__ beta1, const float* __restrict__ intercepts,
    const float* __restrict__ wz, const float* __restrict__ wx,
    const float* __restrict__ logvar_u,
    float* __restrict__ linpar_out, float* __restrict__ condmean_out)
{
    const int wave = threadIdx.x >> 6;
    const int lane = threadIdx.x & 63;
    const int b    = blockIdx.x * 4 + wave;
    const int v    = lane;

    float wxv[CC];
#pragma unroll
    for (int c = 0; c < CC; ++c) wxv[c] = wx[c * VV + v];
    float wzv[LL];
#pragma unroll
    for (int l = 0; l < LL; ++l) wzv[l] = wz[l * VV + v];
    const float base = intercepts[v] + u[(size_t)b * VV + v] * __expf(0.5f * logvar_u[v]);

    float Ar[LL][LL];
#pragma unroll
    for (int l = 0; l < LL; ++l)
#pragma unroll
        for (int j = 0; j < LL; ++j) Ar[l][j] = A[l * LL + j];
    float b0[LL], b1[LL];
#pragma unroll
    for (int j = 0; j < LL; ++j) { b0[j] = beta0[j]; b1[j] = beta1[j]; }

    const float* epsb = eps + (size_t)b * TT * LL;
    const float* xb   = x   + (size_t)b * TT * CC;
    float* lp = linpar_out   + (size_t)b * TT * VV + v;
    float* cm = condmean_out + (size_t)b * TT * VV + v;

    float z[LL];
#pragma unroll
    for (int j = 0; j < LL; ++j) z[j] = epsb[j] * __expf(0.5f * logvar_z1[j]);

    for (int t = 0; t < TT; ++t) {
        if (t > 0) {
            float zn[LL];
            const float tf = (float)t;
#pragma unroll
            for (int j = 0; j < LL; ++j) {
                float a = fmaf(b1[j], tf, b0[j]) + epsb[t * LL + j];
#pragma unroll
                for (int l = 0; l < LL; ++l) a = fmaf(z[l], Ar[l][j], a);
                zn[j] = a;
            }
#pragma unroll
            for (int j = 0; j < LL; ++j) z[j] = zn[j];
        }
        float acc = base;
#pragma unroll
        for (int c = 0; c < CC; ++c) acc = fmaf(xb[t * CC + c], wxv[c], acc);
#pragma unroll
        for (int l = 0; l < LL; ++l) acc = fmaf(z[l], wzv[l], acc);
        acc = fminf(fmaxf(acc, -CLIP), CLIP);
        float cmv = (v < NBERN) ? (1.0f / (1.0f + __expf(-acc))) : __expf(acc);
        lp[(size_t)t * VV] = acc;
        cm[(size_t)t * VV] = cmv;
    }
}

extern "C" void kernel_launch(void* const* d_in, const int* in_sizes, int n_in,
                              void* d_out, int out_size, void* d_ws, size_t ws_size,
                              hipStream_t stream) {
    const float* eps        = (const float*)d_in[0];
    const float* u          = (const float*)d_in[1];
    const float* x          = (const float*)d_in[2];
    const float* A          = (const float*)d_in[3];
    const float* logvar_z1  = (const float*)d_in[4];
    const float* beta0      = (const float*)d_in[5];
    const float* beta1      = (const float*)d_in[6];
    const float* intercepts = (const float*)d_in[7];
    const float* wz         = (const float*)d_in[8];
    const float* wx         = (const float*)d_in[9];
    const float* logvar_u   = (const float*)d_in[10];

    float* linpar   = (float*)d_out;
    float* condmean = (float*)d_out + (size_t)BB * TT * VV;

    const size_t z_bytes = (size_t)BB * TT * LL * sizeof(float);
    if (ws_size >= z_bytes) {
        float* zws = (float*)d_ws;
        hipLaunchKernelGGL(var1_kernel, dim3(BB / 64), dim3(64), 0, stream,
                           eps, A, logvar_z1, beta0, beta1, zws);
        const int nwaves = BB * NCH;
        hipLaunchKernelGGL(link_kernel, dim3(nwaves / 4), dim3(256), 0, stream,
                           zws, u, x, intercepts, wz, wx, logvar_u, linpar, condmean);
    } else {
        hipLaunchKernelGGL(vargllvm_fused, dim3(BB / 4), dim3(256), 0, stream,
                           eps, u, x, A, logvar_z1, beta0, beta1,
                           intercepts, wz, wx, logvar_u, linpar, condmean);
    }
}